// Round 2
// baseline (205.449 us; speedup 1.0000x reference)
//
#include <hip/hip_runtime.h>
#include <math.h>

// Gate / MoE router: logits = x @ W^T (T=16384, D=2048, E=8), softmax, top-2,
// renormalize. out = [T*2] weights (fp32) ++ [T*2] indices (as fp32).
//
// Renormalized top-2 softmax: w1 = 1/(1+exp(l2-l1)), w2 = 1-w1 (Z cancels).
//
// R2 change vs R1: value-splitting exchange butterfly (31+1 shuffles instead
// of 192) + nontemporal x loads (x has zero reuse; keep it out of L2 so W
// re-reads stay hot).

constexpr int D = 2048;
constexpr int E = 8;
constexpr int NT = 16384;
constexpr int T_PER_WAVE = 4;       // tokens per wave
constexpr int WAVES_PER_BLOCK = 4;  // 256-thread blocks
constexpr int BLOCK = WAVES_PER_BLOCK * 64;
constexpr int CHUNK = 64 * 4;       // floats per wave per K-iteration
constexpr int NV = T_PER_WAVE * E;  // 32 partial values per lane

typedef float fvec4 __attribute__((ext_vector_type(4)));

__global__ __launch_bounds__(BLOCK) void gate_kernel(
    const float* __restrict__ x, const float* __restrict__ W,
    float* __restrict__ out) {
  const int lane = threadIdx.x & 63;
  const int wslot = threadIdx.x >> 6;
  const int wave = blockIdx.x * WAVES_PER_BLOCK + wslot;
  const int t0 = wave * T_PER_WAVE;  // first token this wave owns

  float v[NV];  // v[t*E+e]
#pragma unroll
  for (int i = 0; i < NV; i++) v[i] = 0.f;

  // K loop: lane l covers k = c*256 + l*4 .. +3 (fully coalesced 1KiB/inst)
  for (int c = 0; c < D / CHUNK; c++) {
    const int k = c * CHUNK + lane * 4;
    fvec4 xv[T_PER_WAVE];
#pragma unroll
    for (int t = 0; t < T_PER_WAVE; t++)
      xv[t] = __builtin_nontemporal_load(
          (const fvec4*)(x + (size_t)(t0 + t) * D + k));
#pragma unroll
    for (int e = 0; e < E; e++) {
      const fvec4 wv = *(const fvec4*)(W + (size_t)e * D + k);
#pragma unroll
      for (int t = 0; t < T_PER_WAVE; t++) {
        v[t * E + e] += xv[t].x * wv.x;
        v[t * E + e] += xv[t].y * wv.y;
        v[t * E + e] += xv[t].z * wv.z;
        v[t * E + e] += xv[t].w * wv.w;
      }
    }
  }

  // Value-splitting exchange butterfly: each step halves both the lane-group
  // size and the values-per-lane. 16+8+4+2+1 = 31 shuffles (vs 192 naive).
  // After the loop, lane L holds the full-wave sum of value (L>>1)&31
  // (duplicated across lane pairs after the final offset-1 add).
  int n = NV / 2;
#pragma unroll
  for (int o = 32; o >= 2; o >>= 1) {
    const bool upper = (lane & o) != 0;
#pragma unroll
    for (int i = 0; i < 16; i++) {  // bound by max n; guard with i<n
      if (i < n) {
        const float send = upper ? v[i] : v[i + n];
        const float keep = upper ? v[i + n] : v[i];
        v[i] = keep + __shfl_xor(send, o, 64);
      }
    }
    n >>= 1;
  }
  const float r = v[0] + __shfl_xor(v[0], 1, 64);

  // Bounce the 32 reduced logits through LDS so 4 lanes can do scalar top-2.
  __shared__ float red[WAVES_PER_BLOCK][NV];
  red[wslot][(lane >> 1) & 31] = r;  // lane pairs write identical values
  __syncthreads();

  if (lane < T_PER_WAVE) {
    const int t = lane;
    float l[E];
#pragma unroll
    for (int e = 0; e < E; e++) l[e] = red[wslot][t * E + e];
    // top-1 (strict > keeps lowest index on ties, matching lax.top_k)
    float m1 = l[0];
    int i1 = 0;
#pragma unroll
    for (int e = 1; e < E; e++)
      if (l[e] > m1) { m1 = l[e]; i1 = e; }
    float m2 = -INFINITY;
    int i2 = 0;
#pragma unroll
    for (int e = 0; e < E; e++)
      if (e != i1 && l[e] > m2) { m2 = l[e]; i2 = e; }
    const float s = __expf(m2 - m1);  // <= 1
    const float w1 = 1.f / (1.f + s);
    // 4 lanes -> 2 contiguous 32B store groups
    *(float2*)(out + 2 * (size_t)(t0 + t)) = make_float2(w1, 1.f - w1);
    *(float2*)(out + 2 * (size_t)NT + 2 * (size_t)(t0 + t)) =
        make_float2((float)i1, (float)i2);
  }
}

extern "C" void kernel_launch(void* const* d_in, const int* in_sizes, int n_in,
                              void* d_out, int out_size, void* d_ws,
                              size_t ws_size, hipStream_t stream) {
  const float* x = (const float*)d_in[0];
  const float* W = (const float*)d_in[1];
  float* out = (float*)d_out;
  const int blocks = NT / (T_PER_WAVE * WAVES_PER_BLOCK);  // 1024
  gate_kernel<<<blocks, BLOCK, 0, stream>>>(x, W, out);
}